// Round 8
// baseline (149.127 us; speedup 1.0000x reference)
//
#include <hip/hip_runtime.h>

// DWN pipeline: ONE dispatch, ONE cheap grid barrier, no cache maintenance.
//
// Round-7 tripwire root-cause: `base` was loaded only by t==0, so reducer
// lanes 1..63 waited on a stale target after the first launch (first run
// correct -> absmax 0.0; replays raced -> graph/launch_once divergence).
// Fix: ALL threads load g_flags[b] (same-address relaxed atomic, hardware
// broadcast) -> target is wave-uniform and correct on every launch.
// Round-7 also VALIDATED: relaxed agent-scope atomic store/load on h2T is
// cross-XCD coherent with no wbl2/inv (first-pass output was bit-correct).
//
// Structure (from round-6 counters: fused kernel was HBM-bound on gather
// amplification, 43MB/pass fetch; barriers cost 13us each due to cache
// maintenance): block = layer-2 output o2 (512 blocks x 512 threads, lane =
// batch row). The 6 needed h1 rows are RECOMPUTED inline (x3 redundancy,
// ~1us VALU) so no P1/P2 cross-block dependency exists. Only h2T (2MB)
// crosses blocks via relaxed agent atomics. ONE flag barrier; only the 10
// reducer blocks wait (non-reducers exit -> no deadlock risk even without
// co-residency). Flags are cumulative device globals -> graph-replay-safe.
// Spin cap turns any surprise into a visible wrong answer, not a hang.
//
// FP expression order preserved verbatim from the harness-verified kernels
// (6-bit code order, P3 LSB-first fold, P4 two-level 10x10 sum, /3.3333333f)
// -> absmax 0.0.

#define FEAT  1024
#define O1    2000
#define O2    1000
#define NCLS  10
#define NB    512
#define NT    512

#define SCOPE_AGENT __HIP_MEMORY_SCOPE_AGENT

// Cumulative barrier flags (zero-init at load; +1 per block per launch ->
// all equal at every launch boundary; replay-safe).
__device__ unsigned g_flags[NB];

// h1[o1, r]: pure 6-bit LUT lookup, recomputed from x/thr (no shared state).
// Bit order and forms identical to the verified kernel: bi -> f = bi/3,
// bit = x[r][f] > thr[bi]; code = b(i0)<<5 | ... | b(i5).
__device__ __forceinline__ float h1_compute(
    const float* __restrict__ x, const float* __restrict__ thr,
    const float* __restrict__ luts1, const int* __restrict__ idx1,
    int o1, int r)
{
    const int2* ip = (const int2*)(idx1 + o1 * 6);   // wave-uniform, 8B-aligned
    const int2 q0 = ip[0], q1 = ip[1], q2 = ip[2];
    const float* xr = x + (size_t)r * FEAT;
    const int b0 = xr[q0.x / 3] > thr[q0.x];
    const int b1 = xr[q0.y / 3] > thr[q0.y];
    const int b2 = xr[q1.x / 3] > thr[q1.x];
    const int b3 = xr[q1.y / 3] > thr[q1.y];
    const int b4 = xr[q2.x / 3] > thr[q2.x];
    const int b5 = xr[q2.y / 3] > thr[q2.y];
    const int code = (b0 << 5) | (b1 << 4) | (b2 << 3)
                   | (b3 << 2) | (b4 << 1) | b5;
    return luts1[o1 * 64 + code];                    // gather in uniform 256B row
}

__global__ __launch_bounds__(NT, 4) void dwn_ob(
    const float* __restrict__ x,       // [512,1024]
    const float* __restrict__ thr,     // [1024,3] == flat [3072]
    const float* __restrict__ luts1,   // [2000,64]
    const int*   __restrict__ idx1,    // [2000,6] in [0,3072)
    const float* __restrict__ luts2,   // [1000,64]
    const int*   __restrict__ idx2,    // [1000,6] in [0,2000)
    float* __restrict__ out,           // [512,10]
    float* __restrict__ h2T)           // ws: [1000][512]
{
    const int t = threadIdx.x;         // = batch row r
    const int b = blockIdx.x;

    // FIX (round-7 tripwire): ALL threads read the block's own flag so
    // `base`/`target` are uniform across every lane on every launch.
    // Own flag is written only by this block -> no read race at start.
    const unsigned base =
        __hip_atomic_load(&g_flags[b], __ATOMIC_RELAXED, SCOPE_AGENT);

    // ---- Phase B: layer 2 outputs, h1 recomputed inline ----
    // Block b handles o2 = b, and o2 = b + 512 when < 1000.
#pragma unroll
    for (int k = 0; k < 2; ++k) {
        const int o2 = b + k * NB;
        if (o2 < O2) {
            const int2* ip = (const int2*)(idx2 + o2 * 6);  // wave-uniform
            const int2 p0 = ip[0], p1 = ip[1], p2 = ip[2];
            const float xv0 = h1_compute(x, thr, luts1, idx1, p0.x, t);
            const float xv1 = h1_compute(x, thr, luts1, idx1, p0.y, t);
            const float xv2 = h1_compute(x, thr, luts1, idx1, p1.x, t);
            const float xv3 = h1_compute(x, thr, luts1, idx1, p1.y, t);
            const float xv4 = h1_compute(x, thr, luts1, idx1, p2.x, t);
            const float xv5 = h1_compute(x, thr, luts1, idx1, p2.y, t);

            const float4* lp = (const float4*)(luts2 + (size_t)o2 * 64);
            float v[16];
#pragma unroll
            for (int q = 0; q < 16; ++q) {   // fold x5 (bit0), x4 (bit1)
                float4 e = lp[q];
                float u0 = e.x + xv5 * (e.y - e.x);
                float u1 = e.z + xv5 * (e.w - e.z);
                v[q] = u0 + xv4 * (u1 - u0);
            }
#pragma unroll
            for (int q = 0; q < 8; ++q) v[q] = v[2*q] + xv3 * (v[2*q+1] - v[2*q]);
#pragma unroll
            for (int q = 0; q < 4; ++q) v[q] = v[2*q] + xv2 * (v[2*q+1] - v[2*q]);
#pragma unroll
            for (int q = 0; q < 2; ++q) v[q] = v[2*q] + xv1 * (v[2*q+1] - v[2*q]);
            const float h2 = v[0] + xv0 * (v[1] - v[0]);

            // Write-through to coherent point: cross-XCD visible, no wbl2
            // (validated by round-7's correct first pass).
            __hip_atomic_store(&h2T[(size_t)o2 * 512 + t], h2,
                               __ATOMIC_RELAXED, SCOPE_AGENT);
        }
    }

    // ---- Barrier arrival: drain block stores, publish own flag ----
    __syncthreads();
    if (t == 0)
        __hip_atomic_store(&g_flags[b], base + 1u, __ATOMIC_RELEASE, SCOPE_AGENT);

    // Non-reducer blocks are done.
    if (b >= NCLS) return;

    // ---- Reducer blocks (0..9): wait for all 512 flags, then P4 ----
    {
        const unsigned target = base + 1u;   // uniform: base loaded by all lanes
        if (t < 64) {
            for (int spin = 0; spin < (1 << 18); ++spin) {
                bool ok = true;
#pragma unroll
                for (int kk = 0; kk < NB / 64; ++kk) {
                    unsigned v = __hip_atomic_load(&g_flags[t + 64 * kk],
                                                   __ATOMIC_RELAXED, SCOPE_AGENT);
                    ok &= (v >= target);
                }
                if (__all(ok)) break;
                __builtin_amdgcn_s_sleep(8);
            }
            __builtin_amdgcn_fence(__ATOMIC_ACQUIRE, "agent");
        }
        __syncthreads();
    }

    // ---- P4: group sum / tau, exact 10x10 two-level order ----
    // Thread t = batch row; block b = class. h2T reads are coherent
    // (atomic) loads, coalesced across lanes.
    {
        const int c = b;
        float s = 0.0f;
#pragma unroll
        for (int p = 0; p < 10; ++p) {
            float s2 = 0.0f;
#pragma unroll
            for (int j = 0; j < 10; ++j) {
                const float hv = __hip_atomic_load(
                    &h2T[(size_t)(c * 100 + p * 10 + j) * 512 + t],
                    __ATOMIC_RELAXED, SCOPE_AGENT);
                s2 += hv;
            }
            s += s2;
        }
        out[t * NCLS + c] = s / 3.3333333f;
    }
}

extern "C" void kernel_launch(void* const* d_in, const int* in_sizes, int n_in,
                              void* d_out, int out_size, void* d_ws, size_t ws_size,
                              hipStream_t stream) {
    const float* x     = (const float*)d_in[0];
    const float* thr   = (const float*)d_in[1];
    const float* luts1 = (const float*)d_in[2];
    const int*   idx1  = (const int*)  d_in[3];
    const float* luts2 = (const float*)d_in[4];
    const int*   idx2  = (const int*)  d_in[5];
    float* out = (float*)d_out;
    float* h2T = (float*)d_ws;         // 2 MB of workspace

    dwn_ob<<<NB, NT, 0, stream>>>(x, thr, luts1, idx1, luts2, idx2, out, h2T);
}

// Round 9
// 117.477 us; speedup vs baseline: 1.2694x; 1.2694x over previous
//
#include <hip/hip_runtime.h>

// DWN pipeline: fully BLOCK-LOCAL, zero cross-block communication.
//
// Evidence trail: R6 = fused row-blocks re-read all tables per block (43MB/
// pass, ~35us, HBM-bound). R4 = every agent release/acquire grid barrier
// costs ~13us (wbl2/inv through poison-dirty L2). R1 = each extra dispatch
// ~10us. R8 = inline h1 recompute from global x is a columnar-gather
// disaster (19M transactions, 92us) though relaxed-atomic coherence works.
// The only structure dodging ALL four: block = (class, 64-row group),
// everything in LDS, bits recomputed per block via staged transpose+ballot.
//
//   grid = 10 classes x 8 row-groups = 80 blocks x 1024 threads (lane=row)
//   P1: stage x tiles (64x64 coalesced float4) -> padded LDS -> column read
//       (2-way banks, free) -> __ballot -> s_bits[3072] u64 (24 KB LDS).
//       x3 thermometer bit order: bit index bi = f*3+j, thr flat [bi].
//   P23: for each of this class's 100 o2: 6 inline h1 lookups (6 LDS u64
//       broadcasts + luts1 gather in a wave-uniform 256B row) + multilinear
//       fold (verbatim fp order) -> s_h2[100][64] LDS.
//   P4: lane=row exact two-level 10x10 sum (verbatim) -> out.
//
// No workspace, no atomics, no grid sync, deterministic -> replay-safe.
// LDS: 24 KB bits + union(16.6 KB x-tile, 25.6 KB h2) = 49 KB < 64 KB.

#define FEAT  1024
#define O1    2000
#define O2    1000
#define NCLS  10
#define NRG   8              // row groups of 64 (8*64 = 512 batch rows)
#define NB    (NCLS * NRG)   // 80 blocks
#define NT    1024           // 16 waves

__global__ __launch_bounds__(NT) void dwn_cls(
    const float* __restrict__ x,       // [512,1024]
    const float* __restrict__ thr,     // [1024,3] == flat [3072]
    const float* __restrict__ luts1,   // [2000,64]
    const int*   __restrict__ idx1,    // [2000,6] in [0,3072)
    const float* __restrict__ luts2,   // [1000,64]
    const int*   __restrict__ idx2,    // [1000,6] in [0,2000)
    float* __restrict__ out)           // [512,10]
{
    __shared__ unsigned long long s_bits[FEAT * 3];     // 24 KB
    __shared__ union {
        float xt[64][65];                               // 16.6 KB (P1 only)
        float h2[100][64];                              // 25.6 KB (P23/P4)
    } u;

    const int t     = threadIdx.x;
    const int lane  = t & 63;
    const int wl    = t >> 6;              // wave in block, 0..15
    const int c     = blockIdx.x / NRG;    // class 0..9
    const int rg    = blockIdx.x % NRG;    // row group 0..7
    const int rbase = rg << 6;             // first batch row of this block

    // ---- P1: thermometer bits for rows rbase..rbase+63, via LDS transpose ----
    for (int ti = 0; ti < FEAT / 64; ++ti) {
        // stage 64 rows x 64 cols, coalesced float4 (16 threads/row)
        {
            const int row = t >> 4;              // 0..63
            const int c4  = (t & 15) << 2;       // 0,4,...,60
            const float4 xv = *(const float4*)(
                x + (size_t)(rbase + row) * FEAT + ti * 64 + c4);
            u.xt[row][c4 + 0] = xv.x;
            u.xt[row][c4 + 1] = xv.y;
            u.xt[row][c4 + 2] = xv.z;
            u.xt[row][c4 + 3] = xv.w;
        }
        __syncthreads();
        // wave wl ballots cols [wl*4, wl*4+4): lane = row
#pragma unroll
        for (int cc = 0; cc < 4; ++cc) {
            const int col = (wl << 2) + cc;      // 0..63, wave-uniform
            const float val = u.xt[lane][col];   // stride-65 -> 2-way, free
            const int f = ti * 64 + col;
            const float* tp = thr + (size_t)f * 3;   // wave-uniform
#pragma unroll
            for (int j = 0; j < 3; ++j) {
                const unsigned long long m = __ballot(val > tp[j]);
                if (lane == 0) s_bits[f * 3 + j] = m;
            }
        }
        __syncthreads();                         // xt reuse + bits ordering
    }
    // s_bits complete; last __syncthreads also fences before u.h2 writes.

    // ---- P23: this class's 100 layer-2 outputs, h1 inline from LDS bits ----
    for (int o2l = wl; o2l < 100; o2l += NT / 64) {
        const int o2 = c * 100 + o2l;
        const int2* ip = (const int2*)(idx2 + o2 * 6);   // wave-uniform
        const int2 p0 = ip[0], p1 = ip[1], p2 = ip[2];

        // h1[o1, row]: 6 LDS u64 broadcasts + luts1 gather (uniform 256B row).
        // Bit order verbatim: code = b(i0)<<5 | ... | b(i5).
        float xv[6];
        const int o1s[6] = {p0.x, p0.y, p1.x, p1.y, p2.x, p2.y};
#pragma unroll
        for (int k = 0; k < 6; ++k) {
            const int o1 = o1s[k];
            const int2* iq = (const int2*)(idx1 + o1 * 6);  // wave-uniform
            const int2 q0 = iq[0], q1 = iq[1], q2 = iq[2];
            const int b0 = (int)((s_bits[q0.x] >> lane) & 1ull);
            const int b1 = (int)((s_bits[q0.y] >> lane) & 1ull);
            const int b2 = (int)((s_bits[q1.x] >> lane) & 1ull);
            const int b3 = (int)((s_bits[q1.y] >> lane) & 1ull);
            const int b4 = (int)((s_bits[q2.x] >> lane) & 1ull);
            const int b5 = (int)((s_bits[q2.y] >> lane) & 1ull);
            const int code = (b0 << 5) | (b1 << 4) | (b2 << 3)
                           | (b3 << 2) | (b4 << 1) | b5;
            xv[k] = luts1[o1 * 64 + code];
        }

        // 6-D multilinear fold, LSB-first — verbatim fp order.
        const float4* lp = (const float4*)(luts2 + (size_t)o2 * 64);  // uniform
        float v[16];
#pragma unroll
        for (int q = 0; q < 16; ++q) {       // fold x5 (bit0), x4 (bit1)
            float4 e = lp[q];
            float u0 = e.x + xv[5] * (e.y - e.x);
            float u1 = e.z + xv[5] * (e.w - e.z);
            v[q] = u0 + xv[4] * (u1 - u0);
        }
#pragma unroll
        for (int q = 0; q < 8; ++q) v[q] = v[2*q] + xv[3] * (v[2*q+1] - v[2*q]);
#pragma unroll
        for (int q = 0; q < 4; ++q) v[q] = v[2*q] + xv[2] * (v[2*q+1] - v[2*q]);
#pragma unroll
        for (int q = 0; q < 2; ++q) v[q] = v[2*q] + xv[1] * (v[2*q+1] - v[2*q]);
        u.h2[o2l][lane] = v[0] + xv[0] * (v[1] - v[0]);
    }
    __syncthreads();

    // ---- P4: group sum / tau, exact 10x10 two-level order (verbatim) ----
    if (wl == 0) {
        float s = 0.0f;
#pragma unroll
        for (int p = 0; p < 10; ++p) {
            float s2 = 0.0f;
#pragma unroll
            for (int j = 0; j < 10; ++j) s2 += u.h2[p * 10 + j][lane];
            s += s2;
        }
        out[(size_t)(rbase + lane) * NCLS + c] = s / 3.3333333f;
    }
}

extern "C" void kernel_launch(void* const* d_in, const int* in_sizes, int n_in,
                              void* d_out, int out_size, void* d_ws, size_t ws_size,
                              hipStream_t stream) {
    const float* x     = (const float*)d_in[0];
    const float* thr   = (const float*)d_in[1];
    const float* luts1 = (const float*)d_in[2];
    const int*   idx1  = (const int*)  d_in[3];
    const float* luts2 = (const float*)d_in[4];
    const int*   idx2  = (const int*)  d_in[5];
    float* out = (float*)d_out;

    dwn_cls<<<NB, NT, 0, stream>>>(x, thr, luts1, idx1, luts2, idx2, out);
}